// Round 6
// baseline (187.668 us; speedup 1.0000x reference)
//
#include <hip/hip_runtime.h>

// ---------------------------------------------------------------------------
// AttentionBlock: GroupNorm -> QKV 1x1 conv -> MHA (8 heads, d=64, N=1024)
//               -> proj 1x1 conv -> +residual
// Shapes: B=8, C=512, H=W=32 (N=1024), groups=32, heads=8, hd=64. fp32 I/O.
// R16->R17: attn only — m169 pattern ("don't LDS-stage L2-fit data"). Per
// (b,h), K+V = 256 KB and all 8 qt-blocks of a head land on XCD h%8 (grid
// linear%8==h), so K/V is L2-resident (2MB/XCD < 4MB). K/V LDS staging +
// ALL 8 inner-loop barriers deleted; K/V fragments loaded direct from
// global (one 128B line per row, full-line coalesced). Waves now fully
// independent across the kv sweep (16 waves/CU, pure TLP latency hiding).
// LDS 64KB -> 35KB (epilogue half-combine buffer only).
// ---------------------------------------------------------------------------

typedef __bf16 bf16;
typedef __bf16 bf16x8 __attribute__((ext_vector_type(8)));
typedef __bf16 bf16x4 __attribute__((ext_vector_type(4)));
typedef float  f32x4  __attribute__((ext_vector_type(4)));
typedef float  f32x16 __attribute__((ext_vector_type(16)));
typedef unsigned u32x4 __attribute__((ext_vector_type(4)));

#define MFMA_16x16x32(A, B, C) __builtin_amdgcn_mfma_f32_16x16x32_bf16((A), (B), (C), 0, 0, 0)
#define MFMA_32x32x16(A, B, C) __builtin_amdgcn_mfma_f32_32x32x16_bf16((A), (B), (C), 0, 0, 0)

static __device__ __forceinline__ unsigned cvt_pk_bf16(float a, float b) {
  unsigned r;
  asm("v_cvt_pk_bf16_f32 %0, %1, %2" : "=v"(r) : "v"(a), "v"(b));
  return r;
}

// Stage a 128-row x 32-k bf16 tile (rows stride 512 in global) into LDS via
// async global_load_lds width=16.
static __device__ __forceinline__ void async_stage_128x32(
    const bf16* __restrict__ g0, bf16* lds, int tid) {
  const int wv = tid >> 6, ln = tid & 63;
#pragma unroll
  for (int cc = 0; cc < 2; ++cc) {
    const int c = wv + cc * 4;                       // wave-uniform chunk id
    const bf16* g = g0 + (size_t)(c * 16 + (ln >> 2)) * 512 + (ln & 3) * 8;
    __builtin_amdgcn_global_load_lds(
        (const __attribute__((address_space(1))) void*)g,
        (__attribute__((address_space(3))) void*)(lds + c * 512),
        16, 0, 0);
  }
}

// 64-row variant (one 16-row chunk per wave).
static __device__ __forceinline__ void async_stage_64x32(
    const bf16* __restrict__ g0, bf16* lds, int tid) {
  const int wv = tid >> 6, ln = tid & 63;
  const bf16* g = g0 + (size_t)(wv * 16 + (ln >> 2)) * 512 + (ln & 3) * 8;
  __builtin_amdgcn_global_load_lds(
      (const __attribute__((address_space(1))) void*)g,
      (__attribute__((address_space(3))) void*)(lds + wv * 512),
      16, 0, 0);
}

// ---------------------------------------------------------------------------
// Kernel 1: fused GroupNorm (stats + apply + transpose) and weight cvt.
__global__ __launch_bounds__(256) void gn_fused_kernel(
    const float* __restrict__ x,
    const float* __restrict__ gn_w, const float* __restrict__ gn_b,
    const float* __restrict__ qw, const float* __restrict__ pw,
    bf16* __restrict__ wq, bf16* __restrict__ wp, bf16* __restrict__ xn_t) {
  const int t = threadIdx.x;
  if (blockIdx.x >= 256) {
    const int idx = (blockIdx.x - 256) * 256 + t;    // float4 id
    if (idx < 196608) {                              // 1536*512/4
      float4 v = ((const float4*)qw)[idx];
      bf16x4 o = { (bf16)v.x, (bf16)v.y, (bf16)v.z, (bf16)v.w };
      *(bf16x4*)(&wq[idx * 4]) = o;
    }
    if (idx < 65536) {                               // 512*512/4
      float4 v = ((const float4*)pw)[idx];
      bf16x4 o = { (bf16)v.x, (bf16)v.y, (bf16)v.z, (bf16)v.w };
      *(bf16x4*)(&wp[idx * 4]) = o;
    }
    return;
  }
  const int bg = blockIdx.x;                        // 0..255
  const int b = bg >> 5, g = bg & 31;
  const int c0 = g * 16;
  const float4* p = (const float4*)(x + ((size_t)b * 512 + c0) * 1024);
  float4 v[16];
  float s = 0.f, s2 = 0.f;
#pragma unroll
  for (int i = 0; i < 16; ++i) {                     // c=i, n=4t..4t+3
    v[i] = p[t + 256 * i];
    s  += (v[i].x + v[i].y) + (v[i].z + v[i].w);
    s2 += (v[i].x * v[i].x + v[i].y * v[i].y) + (v[i].z * v[i].z + v[i].w * v[i].w);
  }
#pragma unroll
  for (int d = 1; d < 64; d <<= 1) {
    s  += __shfl_xor(s,  d);
    s2 += __shfl_xor(s2, d);
  }
  __shared__ float as[4], as2[4];
  __shared__ float scs[16], shs[16];
  if ((t & 63) == 0) { as[t >> 6] = s; as2[t >> 6] = s2; }
  __syncthreads();
  if (t < 16) {
    float S  = as[0] + as[1] + as[2] + as[3];
    float S2 = as2[0] + as2[1] + as2[2] + as2[3];
    float m  = S * (1.0f / 16384.0f);
    float rs = rsqrtf(S2 * (1.0f / 16384.0f) - m * m + 1e-5f);
    float sc = rs * gn_w[c0 + t];
    scs[t] = sc;
    shs[t] = gn_b[c0 + t] - m * sc;
  }
  __syncthreads();
  bf16* ob = xn_t + ((size_t)b * 1024 + 4 * t) * 512 + c0;
#pragma unroll
  for (int j = 0; j < 4; ++j) {                      // n = 4t + j
    bf16 tmp[16];
#pragma unroll
    for (int i = 0; i < 16; ++i) {
      float val = (j == 0) ? v[i].x : (j == 1) ? v[i].y : (j == 2) ? v[i].z : v[i].w;
      tmp[i] = (bf16)(val * scs[i] + shs[i]);
    }
    *(bf16x8*)(ob + (size_t)j * 512)     = *(bf16x8*)(tmp);
    *(bf16x8*)(ob + (size_t)j * 512 + 8) = *(bf16x8*)(tmp + 8);
  }
}

// ---------------------------------------------------------------------------
// Kernel 2: QKV GEMM, single-barrier dbuf K-loop (BK=32, 16 iters).
__global__ __launch_bounds__(256) void qkv_gemm_kernel(
    const bf16* __restrict__ W, const bf16* __restrict__ xn_t,
    const float* __restrict__ qkv_b, bf16* __restrict__ qkv_t,
    bf16* __restrict__ v_t) {
  const int n0 = blockIdx.x * 128;
  const int o0 = blockIdx.y * 128;
  const int b  = blockIdx.z;
  __shared__ bf16 As[2][128 * 32];
  __shared__ bf16 Bs[2][128 * 32];
  const int tid = threadIdx.x, ln = tid & 63, wv = tid >> 6;
  const int mw = (wv >> 1) * 64, nw = (wv & 1) * 64;
  const int l15 = ln & 15, lg = ln >> 4;
  const bool isV = (o0 >= 1024);
  const bf16* gA = W + (size_t)o0 * 512;
  const bf16* gB = xn_t + ((size_t)b * 1024 + n0) * 512;
  f32x4 acc[4][4] = {};
  async_stage_128x32(gA, As[0], tid);
  async_stage_128x32(gB, Bs[0], tid);
  for (int it = 0; it < 16; ++it) {
    __syncthreads();                                 // publish buf[cur]
    const int cur = it & 1, nxt = cur ^ 1;
    if (it < 15) {                                   // prefetch overlaps compute
      async_stage_128x32(gA + (it + 1) * 32, As[nxt], tid);
      async_stage_128x32(gB + (it + 1) * 32, Bs[nxt], tid);
    }
    bf16x8 af[4], bfr[4];
#pragma unroll
    for (int mi = 0; mi < 4; ++mi)
      af[mi] = *(const bf16x8*)(&As[cur][(mw + mi * 16 + l15) * 32 + lg * 8]);
#pragma unroll
    for (int nj = 0; nj < 4; ++nj)
      bfr[nj] = *(const bf16x8*)(&Bs[cur][(nw + nj * 16 + l15) * 32 + lg * 8]);
    if (!isV) {
#pragma unroll
      for (int mi = 0; mi < 4; ++mi)
#pragma unroll
        for (int nj = 0; nj < 4; ++nj)
          acc[mi][nj] = MFMA_16x16x32(af[mi], bfr[nj], acc[mi][nj]);
    } else {                                         // swapped: acc = D^T
#pragma unroll
      for (int mi = 0; mi < 4; ++mi)
#pragma unroll
        for (int nj = 0; nj < 4; ++nj)
          acc[mi][nj] = MFMA_16x16x32(bfr[nj], af[mi], acc[mi][nj]);
    }
  }
  if (!isV) {
    const float qs = (o0 < 512) ? 0.125f * 1.44269504089f : 1.0f;
#pragma unroll
    for (int mi = 0; mi < 4; ++mi) {
      const int o = o0 + mw + mi * 16 + lg * 4;
      const float b0 = qkv_b[o], b1 = qkv_b[o + 1], b2 = qkv_b[o + 2], b3 = qkv_b[o + 3];
#pragma unroll
      for (int nj = 0; nj < 4; ++nj) {
        const int n = n0 + nw + nj * 16 + l15;
        f32x4 v = acc[mi][nj];
        bf16x4 st = { (bf16)((v.x + b0) * qs), (bf16)((v.y + b1) * qs),
                      (bf16)((v.z + b2) * qs), (bf16)((v.w + b3) * qs) };
        *(bf16x4*)(&qkv_t[((size_t)b * 1024 + n) * 1536 + o]) = st;
      }
    }
  } else {
    // swapped C-layout: lane holds D[n = nw+nj*16+lg*4+r][o = mw+mi*16+l15]
#pragma unroll
    for (int mi = 0; mi < 4; ++mi) {
      const int o  = o0 + mw + mi * 16 + l15;
      const int hd = o - 1024;                       // h*64 + d
      const float bias = qkv_b[o];
#pragma unroll
      for (int nj = 0; nj < 4; ++nj) {
        const int n = n0 + nw + nj * 16 + lg * 4;
        f32x4 v = acc[mi][nj];
        bf16x4 st = { (bf16)(v.x + bias), (bf16)(v.y + bias),
                      (bf16)(v.z + bias), (bf16)(v.w + bias) };
        *(bf16x4*)(&v_t[((size_t)b * 512 + hd) * 1024 + n]) = st;
      }
    }
  }
}

// ---------------------------------------------------------------------------
// Kernel 3: fused attention, NO K/V staging (L2-resident direct reads).
// 8 waves = 2 kv-halves x 4 q-subtiles(32 q); half h sweeps kv tiles
// [h*8, h*8+8) with ZERO barriers. 32x32x16 MFMA, swapped QK^T; exp2 in
// regs; P->B-frag via v_cvt_pk_bf16_f32 + v_permlane32_swap_b32. K rows
// (3072B stride, 128B head slice) and V rows (2048B stride, 128B tile
// slice) are one L2 line each, full-line coalesced. Halves combine O/l
// via f32 LDS exchange at the end (only LDS use in the kernel).
__global__ __launch_bounds__(512, 4) void attn_kernel(
    const bf16* __restrict__ qkv_t, const bf16* __restrict__ v_t,
    bf16* __restrict__ at_t) {
  const int qt = blockIdx.y;                        // 0..7 (128 q each)
  const int b  = blockIdx.x >> 3;
  const int h  = blockIdx.x & 7;
  __shared__ __align__(16) char smem[35328];        // epilogue exchange only
  const int tid = threadIdx.x, ln = tid & 63, wv = tid >> 6;
  const int half = wv >> 2, w4 = wv & 3;
  const int l31 = ln & 31, hi = ln >> 5;
  const bf16* hq  = qkv_t + (size_t)b * 1024 * 1536 + h * 64;
  const bf16* hk  = hq + 512;
  const bf16* vtb = v_t + (size_t)(b * 8 + h) * 64 * 1024;

  const int qb = qt * 128 + w4 * 32;
  // Q B-fragments: lane holds q=l31, d = ks*16 + hi*8 + j
  bf16x8 qf[4];
#pragma unroll
  for (int ks = 0; ks < 4; ++ks)
    qf[ks] = *(const bf16x8*)(hq + (size_t)(qb + l31) * 1536 + ks * 16 + hi * 8);

  f32x16 oacc[2] = {};                              // O^T[d-tile][q]
  float lst = 0.f;
  const int kt0 = half * 8;

  for (int i = 0; i < 8; ++i) {
    const int kt = kt0 + i;
    const bf16* kb = hk  + (size_t)(kt * 64) * 1536;
    const bf16* vb = vtb + kt * 64;

#pragma unroll
    for (int kk = 0; kk < 2; ++kk) {
      const int kvb = kk * 32;
      const int krow = kvb + l31;
      // K fragments direct from global (L2): lane (l31,hi) reads 16B at
      // row krow, d = ks*16+hi*8.
      bf16x8 kf[4];
#pragma unroll
      for (int ks = 0; ks < 4; ++ks)
        kf[ks] = *(const bf16x8*)(kb + (size_t)krow * 1536 + ks * 16 + hi * 8);
      f32x16 st = {};
#pragma unroll
      for (int ks = 0; ks < 4; ++ks)
        st = MFMA_32x32x16(kf[ks], qf[ks], st);
#pragma unroll
      for (int r = 0; r < 16; ++r) st[r] = exp2f(st[r]);
      lst += ((st[0] + st[1]) + (st[2] + st[3])) + ((st[4] + st[5]) + (st[6] + st[7]))
           + ((st[8] + st[9]) + (st[10] + st[11])) + ((st[12] + st[13]) + (st[14] + st[15]));
#pragma unroll
      for (int t = 0; t < 2; ++t) {
        // own regs hold kv rows crow(r,hi); swap lane-halves to build B-frag
        // (lane needs kv = t*16 + hi*8 + j). After swap: {x0,x1,y0,y1} are
        // the 4 B-frag words in order.
        unsigned x0 = cvt_pk_bf16(st[t * 8 + 0], st[t * 8 + 1]);
        unsigned x1 = cvt_pk_bf16(st[t * 8 + 2], st[t * 8 + 3]);
        unsigned y0 = cvt_pk_bf16(st[t * 8 + 4], st[t * 8 + 5]);
        unsigned y1 = cvt_pk_bf16(st[t * 8 + 6], st[t * 8 + 7]);
        asm("v_permlane32_swap_b32 %0, %1" : "+v"(x0), "+v"(y0));
        asm("v_permlane32_swap_b32 %0, %1" : "+v"(x1), "+v"(y1));
        u32x4 pu = { x0, x1, y0, y1 };
        bf16x8 pb = __builtin_bit_cast(bf16x8, pu);
#pragma unroll
        for (int dt = 0; dt < 2; ++dt) {
          // V^T fragments direct from global (L2): row d = dt*32+l31,
          // cols kvb + t*16 + hi*8 (.. +8), contiguous 16B.
          bf16x8 vf = *(const bf16x8*)(
              vb + (size_t)(dt * 32 + l31) * 1024 + kvb + t * 16 + hi * 8);
          oacc[dt] = MFMA_32x32x16(vf, pb, oacc[dt]);
        }
      }
    }
  }

  // lanes l / l+32 hold complementary kv rows for the same q (within half)
  const float lf = lst + __shfl_xor(lst, 32);

  // combine halves: half 1 publishes O^T + l via LDS; half 0 merges+stores.
  float* MB  = (float*)smem;                        // [w4][32 q][68 d-stride]
  float* MLb = (float*)(smem + 34816);              // [w4][32]
  __syncthreads();
  if (half == 1) {
    float* mb = MB + w4 * (32 * 68);
#pragma unroll
    for (int dt = 0; dt < 2; ++dt)
#pragma unroll
      for (int rr = 0; rr < 4; ++rr) {
        f32x4 v = { oacc[dt][rr * 4 + 0], oacc[dt][rr * 4 + 1],
                    oacc[dt][rr * 4 + 2], oacc[dt][rr * 4 + 3] };
        *(f32x4*)(mb + l31 * 68 + dt * 32 + rr * 8 + hi * 4) = v;
      }
    if (hi == 0) MLb[w4 * 32 + l31] = lf;
  }
  __syncthreads();
  if (half == 0) {
    const float* mb = MB + w4 * (32 * 68);
    const float inv = 1.0f / (lf + MLb[w4 * 32 + l31]);
    const int q = qb + l31;
    bf16* ob = at_t + ((size_t)b * 1024 + q) * 512 + h * 64;
#pragma unroll
    for (int dt = 0; dt < 2; ++dt)
#pragma unroll
      for (int rr = 0; rr < 4; ++rr) {
        f32x4 obv = *(const f32x4*)(mb + l31 * 68 + dt * 32 + rr * 8 + hi * 4);
        bf16x4 ov = { (bf16)((oacc[dt][rr * 4 + 0] + obv[0]) * inv),
                      (bf16)((oacc[dt][rr * 4 + 1] + obv[1]) * inv),
                      (bf16)((oacc[dt][rr * 4 + 2] + obv[2]) * inv),
                      (bf16)((oacc[dt][rr * 4 + 3] + obv[3]) * inv) };
        *(bf16x4*)(ob + dt * 32 + rr * 8 + hi * 4) = ov;
      }
  }
}

// ---------------------------------------------------------------------------
// Kernel 4: proj GEMM + bias + residual. BM=64, single-barrier dbuf (BK=32).
__global__ __launch_bounds__(256) void proj_gemm_kernel(
    const bf16* __restrict__ at_t, const bf16* __restrict__ wp,
    const float* __restrict__ proj_b, const float* __restrict__ x,
    float* __restrict__ out) {
  const int i0 = blockIdx.x * 64;                   // token tile (64)
  const int c0 = blockIdx.y * 128;                  // out-channel tile (128)
  const int b  = blockIdx.z;
  __shared__ bf16 As[2][64 * 32];
  __shared__ bf16 Bs[2][128 * 32];
  const int tid = threadIdx.x, ln = tid & 63, wv = tid >> 6;
  const int mw = (wv >> 1) * 32, nw = (wv & 1) * 64;
  const int l15 = ln & 15, lg = ln >> 4;
  const bf16* gA = at_t + ((size_t)b * 1024 + i0) * 512;
  const bf16* gB = wp + (size_t)c0 * 512;
  f32x4 acc[2][4] = {};
  async_stage_64x32(gA, As[0], tid);
  async_stage_128x32(gB, Bs[0], tid);
  for (int it = 0; it < 16; ++it) {
    __syncthreads();
    const int cur = it & 1, nxt = cur ^ 1;
    if (it < 15) {
      async_stage_64x32(gA + (it + 1) * 32, As[nxt], tid);
      async_stage_128x32(gB + (it + 1) * 32, Bs[nxt], tid);
    }
    bf16x8 af[2], bfr[4];
#pragma unroll
    for (int mi = 0; mi < 2; ++mi)
      af[mi] = *(const bf16x8*)(&As[cur][(mw + mi * 16 + l15) * 32 + lg * 8]);
#pragma unroll
    for (int nj = 0; nj < 4; ++nj)
      bfr[nj] = *(const bf16x8*)(&Bs[cur][(nw + nj * 16 + l15) * 32 + lg * 8]);
#pragma unroll
    for (int mi = 0; mi < 2; ++mi)
#pragma unroll
      for (int nj = 0; nj < 4; ++nj)
        acc[mi][nj] = MFMA_16x16x32(af[mi], bfr[nj], acc[mi][nj]);
  }
#pragma unroll
  for (int mi = 0; mi < 2; ++mi) {
    const int i = i0 + mw + mi * 16 + lg * 4;
#pragma unroll
    for (int nj = 0; nj < 4; ++nj) {
      const int c = c0 + nw + nj * 16 + l15;
      const float bias = proj_b[c];
      const size_t off = ((size_t)b * 512 + c) * 1024 + i;
      const float4 res = *(const float4*)(x + off);
      f32x4 v = acc[mi][nj];
      float4 ov;
      ov.x = v.x + bias + res.x;
      ov.y = v.y + bias + res.y;
      ov.z = v.z + bias + res.z;
      ov.w = v.w + bias + res.w;
      *(float4*)(out + off) = ov;
    }
  }
}

// ---------------------------------------------------------------------------
extern "C" void kernel_launch(void* const* d_in, const int* in_sizes, int n_in,
                              void* d_out, int out_size, void* d_ws, size_t ws_size,
                              hipStream_t stream) {
  (void)in_sizes; (void)n_in; (void)out_size; (void)ws_size;
  const float* x      = (const float*)d_in[0];
  const float* gn_w   = (const float*)d_in[1];
  const float* gn_b   = (const float*)d_in[2];
  const float* qkv_w  = (const float*)d_in[3];
  const float* qkv_b  = (const float*)d_in[4];
  const float* proj_w = (const float*)d_in[5];
  const float* proj_b = (const float*)d_in[6];
  float* out = (float*)d_out;

  // workspace layout (~100 MB)
  char* ws = (char*)d_ws;
  bf16* wq    = (bf16*)ws;                          // [1536][512]
  bf16* wp    = wq + (size_t)1536 * 512;            // [512][512]
  bf16* xn_t  = wp + (size_t)512 * 512;             // [8][1024][512]
  bf16* qkv_t = xn_t + (size_t)8 * 1024 * 512;      // [8][1024][1536] (Q,K only)
  bf16* at_t  = qkv_t + (size_t)8 * 1024 * 1536;    // [8][1024][512]
  bf16* v_t   = at_t + (size_t)8 * 1024 * 512;      // [8][8][64][1024]

  hipLaunchKernelGGL(gn_fused_kernel, dim3(1280),     dim3(256), 0, stream,
                     x, gn_w, gn_b, qkv_w, proj_w, wq, wp, xn_t);
  hipLaunchKernelGGL(qkv_gemm_kernel, dim3(8, 12, 8), dim3(256), 0, stream,
                     wq, xn_t, qkv_b, qkv_t, v_t);
  hipLaunchKernelGGL(attn_kernel,     dim3(64, 8),    dim3(512), 0, stream,
                     qkv_t, v_t, at_t);
  hipLaunchKernelGGL(proj_gemm_kernel,dim3(16, 4, 8), dim3(256), 0, stream,
                     at_t, wp, proj_b, x, out);
}

// Round 7
// 156.082 us; speedup vs baseline: 1.2024x; 1.2024x over previous
//
#include <hip/hip_runtime.h>

// ---------------------------------------------------------------------------
// AttentionBlock: GroupNorm -> QKV 1x1 conv -> MHA (8 heads, d=64, N=1024)
//               -> proj 1x1 conv -> +residual
// Shapes: B=8, C=512, H=W=32 (N=1024), groups=32, heads=8, hd=64. fp32 I/O.
// R17->R18: (1) attn reverted to R12-EXACT (measured best 154.2; R17's
// unstaged variant was load-latency-bound at 64 VGPR, MfmaUtil 9% -> LDS
// staging is latency decoupling, keep it). (2) qkv_gemm: XCD-aware swizzle
// (T1) -- grid flattened to 768, swz=(wgid&7)*96+(wgid>>3) gives each XCD
// exactly one batch: per-XCD L2 working set 3.5MB (W 1.5 + X_b 2.0) < 4MB,
// vs round-robin touching all batches (16.8MB thrash). 768%8==0 bijective.
// ---------------------------------------------------------------------------

typedef __bf16 bf16;
typedef __bf16 bf16x8 __attribute__((ext_vector_type(8)));
typedef __bf16 bf16x4 __attribute__((ext_vector_type(4)));
typedef float  f32x4  __attribute__((ext_vector_type(4)));
typedef float  f32x16 __attribute__((ext_vector_type(16)));
typedef unsigned u32x4 __attribute__((ext_vector_type(4)));

#define MFMA_16x16x32(A, B, C) __builtin_amdgcn_mfma_f32_16x16x32_bf16((A), (B), (C), 0, 0, 0)
#define MFMA_32x32x16(A, B, C) __builtin_amdgcn_mfma_f32_32x32x16_bf16((A), (B), (C), 0, 0, 0)

static __device__ __forceinline__ unsigned cvt_pk_bf16(float a, float b) {
  unsigned r;
  asm("v_cvt_pk_bf16_f32 %0, %1, %2" : "=v"(r) : "v"(a), "v"(b));
  return r;
}

// Stage a 128-row x 32-k bf16 tile (rows stride 512 in global) into LDS via
// async global_load_lds width=16.
static __device__ __forceinline__ void async_stage_128x32(
    const bf16* __restrict__ g0, bf16* lds, int tid) {
  const int wv = tid >> 6, ln = tid & 63;
#pragma unroll
  for (int cc = 0; cc < 2; ++cc) {
    const int c = wv + cc * 4;                       // wave-uniform chunk id
    const bf16* g = g0 + (size_t)(c * 16 + (ln >> 2)) * 512 + (ln & 3) * 8;
    __builtin_amdgcn_global_load_lds(
        (const __attribute__((address_space(1))) void*)g,
        (__attribute__((address_space(3))) void*)(lds + c * 512),
        16, 0, 0);
  }
}

// 64-row variant (one 16-row chunk per wave).
static __device__ __forceinline__ void async_stage_64x32(
    const bf16* __restrict__ g0, bf16* lds, int tid) {
  const int wv = tid >> 6, ln = tid & 63;
  const bf16* g = g0 + (size_t)(wv * 16 + (ln >> 2)) * 512 + (ln & 3) * 8;
  __builtin_amdgcn_global_load_lds(
      (const __attribute__((address_space(1))) void*)g,
      (__attribute__((address_space(3))) void*)(lds + wv * 512),
      16, 0, 0);
}

// ---------------------------------------------------------------------------
// Kernel 1: fused GroupNorm (stats + apply + transpose) and weight cvt.
__global__ __launch_bounds__(256) void gn_fused_kernel(
    const float* __restrict__ x,
    const float* __restrict__ gn_w, const float* __restrict__ gn_b,
    const float* __restrict__ qw, const float* __restrict__ pw,
    bf16* __restrict__ wq, bf16* __restrict__ wp, bf16* __restrict__ xn_t) {
  const int t = threadIdx.x;
  if (blockIdx.x >= 256) {
    const int idx = (blockIdx.x - 256) * 256 + t;    // float4 id
    if (idx < 196608) {                              // 1536*512/4
      float4 v = ((const float4*)qw)[idx];
      bf16x4 o = { (bf16)v.x, (bf16)v.y, (bf16)v.z, (bf16)v.w };
      *(bf16x4*)(&wq[idx * 4]) = o;
    }
    if (idx < 65536) {                               // 512*512/4
      float4 v = ((const float4*)pw)[idx];
      bf16x4 o = { (bf16)v.x, (bf16)v.y, (bf16)v.z, (bf16)v.w };
      *(bf16x4*)(&wp[idx * 4]) = o;
    }
    return;
  }
  const int bg = blockIdx.x;                        // 0..255
  const int b = bg >> 5, g = bg & 31;
  const int c0 = g * 16;
  const float4* p = (const float4*)(x + ((size_t)b * 512 + c0) * 1024);
  float4 v[16];
  float s = 0.f, s2 = 0.f;
#pragma unroll
  for (int i = 0; i < 16; ++i) {                     // c=i, n=4t..4t+3
    v[i] = p[t + 256 * i];
    s  += (v[i].x + v[i].y) + (v[i].z + v[i].w);
    s2 += (v[i].x * v[i].x + v[i].y * v[i].y) + (v[i].z * v[i].z + v[i].w * v[i].w);
  }
#pragma unroll
  for (int d = 1; d < 64; d <<= 1) {
    s  += __shfl_xor(s,  d);
    s2 += __shfl_xor(s2, d);
  }
  __shared__ float as[4], as2[4];
  __shared__ float scs[16], shs[16];
  if ((t & 63) == 0) { as[t >> 6] = s; as2[t >> 6] = s2; }
  __syncthreads();
  if (t < 16) {
    float S  = as[0] + as[1] + as[2] + as[3];
    float S2 = as2[0] + as2[1] + as2[2] + as2[3];
    float m  = S * (1.0f / 16384.0f);
    float rs = rsqrtf(S2 * (1.0f / 16384.0f) - m * m + 1e-5f);
    float sc = rs * gn_w[c0 + t];
    scs[t] = sc;
    shs[t] = gn_b[c0 + t] - m * sc;
  }
  __syncthreads();
  bf16* ob = xn_t + ((size_t)b * 1024 + 4 * t) * 512 + c0;
#pragma unroll
  for (int j = 0; j < 4; ++j) {                      // n = 4t + j
    bf16 tmp[16];
#pragma unroll
    for (int i = 0; i < 16; ++i) {
      float val = (j == 0) ? v[i].x : (j == 1) ? v[i].y : (j == 2) ? v[i].z : v[i].w;
      tmp[i] = (bf16)(val * scs[i] + shs[i]);
    }
    *(bf16x8*)(ob + (size_t)j * 512)     = *(bf16x8*)(tmp);
    *(bf16x8*)(ob + (size_t)j * 512 + 8) = *(bf16x8*)(tmp + 8);
  }
}

// ---------------------------------------------------------------------------
// Kernel 2: QKV GEMM, single-barrier dbuf K-loop (BK=32, 16 iters).
// Flattened 1D grid with XCD swizzle: each XCD owns one batch b.
__global__ __launch_bounds__(256) void qkv_gemm_kernel(
    const bf16* __restrict__ W, const bf16* __restrict__ xn_t,
    const float* __restrict__ qkv_b, bf16* __restrict__ qkv_t,
    bf16* __restrict__ v_t) {
  const int wgid = blockIdx.x;                      // 0..767
  const int swz  = (wgid & 7) * 96 + (wgid >> 3);   // XCD k -> blocks [96k,96k+96)
  const int n0 = (swz & 7) * 128;                   // token tile
  const int o0 = ((swz >> 3) % 12) * 128;           // out-channel tile
  const int b  = swz / 96;                          // batch == XCD id
  __shared__ bf16 As[2][128 * 32];
  __shared__ bf16 Bs[2][128 * 32];
  const int tid = threadIdx.x, ln = tid & 63, wv = tid >> 6;
  const int mw = (wv >> 1) * 64, nw = (wv & 1) * 64;
  const int l15 = ln & 15, lg = ln >> 4;
  const bool isV = (o0 >= 1024);
  const bf16* gA = W + (size_t)o0 * 512;
  const bf16* gB = xn_t + ((size_t)b * 1024 + n0) * 512;
  f32x4 acc[4][4] = {};
  async_stage_128x32(gA, As[0], tid);
  async_stage_128x32(gB, Bs[0], tid);
  for (int it = 0; it < 16; ++it) {
    __syncthreads();                                 // publish buf[cur]
    const int cur = it & 1, nxt = cur ^ 1;
    if (it < 15) {                                   // prefetch overlaps compute
      async_stage_128x32(gA + (it + 1) * 32, As[nxt], tid);
      async_stage_128x32(gB + (it + 1) * 32, Bs[nxt], tid);
    }
    bf16x8 af[4], bfr[4];
#pragma unroll
    for (int mi = 0; mi < 4; ++mi)
      af[mi] = *(const bf16x8*)(&As[cur][(mw + mi * 16 + l15) * 32 + lg * 8]);
#pragma unroll
    for (int nj = 0; nj < 4; ++nj)
      bfr[nj] = *(const bf16x8*)(&Bs[cur][(nw + nj * 16 + l15) * 32 + lg * 8]);
    if (!isV) {
#pragma unroll
      for (int mi = 0; mi < 4; ++mi)
#pragma unroll
        for (int nj = 0; nj < 4; ++nj)
          acc[mi][nj] = MFMA_16x16x32(af[mi], bfr[nj], acc[mi][nj]);
    } else {                                         // swapped: acc = D^T
#pragma unroll
      for (int mi = 0; mi < 4; ++mi)
#pragma unroll
        for (int nj = 0; nj < 4; ++nj)
          acc[mi][nj] = MFMA_16x16x32(bfr[nj], af[mi], acc[mi][nj]);
    }
  }
  if (!isV) {
    const float qs = (o0 < 512) ? 0.125f * 1.44269504089f : 1.0f;
#pragma unroll
    for (int mi = 0; mi < 4; ++mi) {
      const int o = o0 + mw + mi * 16 + lg * 4;
      const float b0 = qkv_b[o], b1 = qkv_b[o + 1], b2 = qkv_b[o + 2], b3 = qkv_b[o + 3];
#pragma unroll
      for (int nj = 0; nj < 4; ++nj) {
        const int n = n0 + nw + nj * 16 + l15;
        f32x4 v = acc[mi][nj];
        bf16x4 st = { (bf16)((v.x + b0) * qs), (bf16)((v.y + b1) * qs),
                      (bf16)((v.z + b2) * qs), (bf16)((v.w + b3) * qs) };
        *(bf16x4*)(&qkv_t[((size_t)b * 1024 + n) * 1536 + o]) = st;
      }
    }
  } else {
    // swapped C-layout: lane holds D[n = nw+nj*16+lg*4+r][o = mw+mi*16+l15]
#pragma unroll
    for (int mi = 0; mi < 4; ++mi) {
      const int o  = o0 + mw + mi * 16 + l15;
      const int hd = o - 1024;                       // h*64 + d
      const float bias = qkv_b[o];
#pragma unroll
      for (int nj = 0; nj < 4; ++nj) {
        const int n = n0 + nw + nj * 16 + lg * 4;
        f32x4 v = acc[mi][nj];
        bf16x4 st = { (bf16)(v.x + bias), (bf16)(v.y + bias),
                      (bf16)(v.z + bias), (bf16)(v.w + bias) };
        *(bf16x4*)(&v_t[((size_t)b * 512 + hd) * 1024 + n]) = st;
      }
    }
  }
}

// ---------------------------------------------------------------------------
// Kernel 3: fused attention (R12-exact, measured best). 8 waves = 2
// kv-halves x 4 q-subtiles(32 q). Swapped QK^T (mfma(K,Q)) gives S^T
// (col=q=lane&31, row=kv=(r&3)+8*(r>>2)+4*(lane>>5)); exp2 in regs;
// P->B-frag via v_cvt_pk_bf16_f32 + v_permlane32_swap_b32 (no P LDS round
// trip). K/V double-buffered in LDS, ONE barrier per tile, reg-prefetch
// issued right after the barrier (T14). Halves combine O/l via f32 LDS
// exchange at the end.
__global__ __launch_bounds__(512, 4) void attn_kernel(
    const bf16* __restrict__ qkv_t, const bf16* __restrict__ v_t,
    bf16* __restrict__ at_t) {
  const int qt = blockIdx.y;                        // 0..7 (128 q each)
  const int b  = blockIdx.x >> 3;
  const int h  = blockIdx.x & 7;
  __shared__ __align__(16) char smem[73728];        // 2 bufs x 2 halves x (K+V)
  const int tid = threadIdx.x, ln = tid & 63, wv = tid >> 6;
  const int half = wv >> 2, w4 = wv & 3;
  const int l31 = ln & 31, hi = ln >> 5;
  const bf16* hq  = qkv_t + (size_t)b * 1024 * 1536 + h * 64;
  const bf16* hk  = hq + 512;
  const bf16* vtb = v_t + (size_t)(b * 8 + h) * 64 * 1024;

  const int qb = qt * 128 + w4 * 32;
  // Q B-fragments: lane holds q=l31, d = ks*16 + hi*8 + j
  bf16x8 qf[4];
#pragma unroll
  for (int ks = 0; ks < 4; ++ks)
    qf[ks] = *(const bf16x8*)(hq + (size_t)(qb + l31) * 1536 + ks * 16 + hi * 8);

  f32x16 oacc[2] = {};                              // O^T[d-tile][q]
  float lst = 0.f;

  const int t256 = tid & 255;
  const int srow = t256 >> 2, scg = (t256 & 3) * 16;
  const int kt0 = half * 8;

  // prologue: stage kv-tile kt0 into buf 0
  bf16x8 s0, s1, s2, s3;
  {
    const bf16* gk = hk  + (size_t)(kt0 * 64 + srow) * 1536 + scg;
    const bf16* gv = vtb + (size_t)srow * 1024 + kt0 * 64 + scg;
    s0 = *(const bf16x8*)(gk);
    s1 = *(const bf16x8*)(gk + 8);
    s2 = *(const bf16x8*)(gv);
    s3 = *(const bf16x8*)(gv + 8);
    bf16* Kt = (bf16*)(smem + half * 18432);
    bf16* Vt = Kt + 64 * 72;
    *(bf16x8*)(&Kt[srow * 72 + scg])     = s0;
    *(bf16x8*)(&Kt[srow * 72 + scg + 8]) = s1;
    *(bf16x8*)(&Vt[srow * 72 + scg])     = s2;
    *(bf16x8*)(&Vt[srow * 72 + scg + 8]) = s3;
  }

  for (int i = 0; i < 8; ++i) {
    __syncthreads();                                 // publish buf[i&1]
    if (i < 7) {                                     // issue prefetch NOW,
      const int kt = kt0 + i + 1;                    // consumed after compute
      const bf16* gk = hk  + (size_t)(kt * 64 + srow) * 1536 + scg;
      const bf16* gv = vtb + (size_t)srow * 1024 + kt * 64 + scg;
      s0 = *(const bf16x8*)(gk);
      s1 = *(const bf16x8*)(gk + 8);
      s2 = *(const bf16x8*)(gv);
      s3 = *(const bf16x8*)(gv + 8);
    }
    const bf16* Kt = (const bf16*)(smem + (i & 1) * 36864 + half * 18432);
    const bf16* Vt = Kt + 64 * 72;

#pragma unroll
    for (int kk = 0; kk < 2; ++kk) {
      const int kvb = kk * 32;
      f32x16 st = {};
#pragma unroll
      for (int ks = 0; ks < 4; ++ks) {
        bf16x8 kf = *(const bf16x8*)(&Kt[(kvb + l31) * 72 + ks * 16 + hi * 8]);
        st = MFMA_32x32x16(kf, qf[ks], st);
      }
#pragma unroll
      for (int r = 0; r < 16; ++r) st[r] = exp2f(st[r]);
      lst += ((st[0] + st[1]) + (st[2] + st[3])) + ((st[4] + st[5]) + (st[6] + st[7]))
           + ((st[8] + st[9]) + (st[10] + st[11])) + ((st[12] + st[13]) + (st[14] + st[15]));
#pragma unroll
      for (int t = 0; t < 2; ++t) {
        // own regs hold kv rows crow(r,hi); swap lane-halves to build B-frag
        // (lane needs kv = t*16 + hi*8 + j). After swap: {x0,x1,y0,y1} are
        // the 4 B-frag words in order.
        unsigned x0 = cvt_pk_bf16(st[t * 8 + 0], st[t * 8 + 1]);
        unsigned x1 = cvt_pk_bf16(st[t * 8 + 2], st[t * 8 + 3]);
        unsigned y0 = cvt_pk_bf16(st[t * 8 + 4], st[t * 8 + 5]);
        unsigned y1 = cvt_pk_bf16(st[t * 8 + 6], st[t * 8 + 7]);
        asm("v_permlane32_swap_b32 %0, %1" : "+v"(x0), "+v"(y0));
        asm("v_permlane32_swap_b32 %0, %1" : "+v"(x1), "+v"(y1));
        u32x4 pu = { x0, x1, y0, y1 };
        bf16x8 pb = __builtin_bit_cast(bf16x8, pu);
#pragma unroll
        for (int dt = 0; dt < 2; ++dt) {
          bf16x8 vf = *(const bf16x8*)(&Vt[(dt * 32 + l31) * 72 + kvb + t * 16 + hi * 8]);
          oacc[dt] = MFMA_32x32x16(vf, pb, oacc[dt]);
        }
      }
    }

    if (i < 7) {                                     // store prefetched tile
      bf16* Ktn = (bf16*)(smem + ((i + 1) & 1) * 36864 + half * 18432);
      bf16* Vtn = Ktn + 64 * 72;
      *(bf16x8*)(&Ktn[srow * 72 + scg])     = s0;
      *(bf16x8*)(&Ktn[srow * 72 + scg + 8]) = s1;
      *(bf16x8*)(&Vtn[srow * 72 + scg])     = s2;
      *(bf16x8*)(&Vtn[srow * 72 + scg + 8]) = s3;
    }
  }

  // lanes l / l+32 hold complementary kv rows for the same q (within half)
  const float lf = lst + __shfl_xor(lst, 32);

  // combine halves: half 1 publishes O^T + l via LDS; half 0 merges+stores.
  float* MB  = (float*)smem;                        // [w4][32 q][68 d-stride]
  float* MLb = (float*)(smem + 34816);              // [w4][32]
  __syncthreads();
  if (half == 1) {
    float* mb = MB + w4 * (32 * 68);
#pragma unroll
    for (int dt = 0; dt < 2; ++dt)
#pragma unroll
      for (int rr = 0; rr < 4; ++rr) {
        f32x4 v = { oacc[dt][rr * 4 + 0], oacc[dt][rr * 4 + 1],
                    oacc[dt][rr * 4 + 2], oacc[dt][rr * 4 + 3] };
        *(f32x4*)(mb + l31 * 68 + dt * 32 + rr * 8 + hi * 4) = v;
      }
    if (hi == 0) MLb[w4 * 32 + l31] = lf;
  }
  __syncthreads();
  if (half == 0) {
    const float* mb = MB + w4 * (32 * 68);
    const float inv = 1.0f / (lf + MLb[w4 * 32 + l31]);
    const int q = qb + l31;
    bf16* ob = at_t + ((size_t)b * 1024 + q) * 512 + h * 64;
#pragma unroll
    for (int dt = 0; dt < 2; ++dt)
#pragma unroll
      for (int rr = 0; rr < 4; ++rr) {
        f32x4 obv = *(const f32x4*)(mb + l31 * 68 + dt * 32 + rr * 8 + hi * 4);
        bf16x4 ov = { (bf16)((oacc[dt][rr * 4 + 0] + obv[0]) * inv),
                      (bf16)((oacc[dt][rr * 4 + 1] + obv[1]) * inv),
                      (bf16)((oacc[dt][rr * 4 + 2] + obv[2]) * inv),
                      (bf16)((oacc[dt][rr * 4 + 3] + obv[3]) * inv) };
        *(bf16x4*)(ob + dt * 32 + rr * 8 + hi * 4) = ov;
      }
  }
}

// ---------------------------------------------------------------------------
// Kernel 4: proj GEMM + bias + residual. BM=64, single-barrier dbuf (BK=32).
__global__ __launch_bounds__(256) void proj_gemm_kernel(
    const bf16* __restrict__ at_t, const bf16* __restrict__ wp,
    const float* __restrict__ proj_b, const float* __restrict__ x,
    float* __restrict__ out) {
  const int i0 = blockIdx.x * 64;                   // token tile (64)
  const int c0 = blockIdx.y * 128;                  // out-channel tile (128)
  const int b  = blockIdx.z;
  __shared__ bf16 As[2][64 * 32];
  __shared__ bf16 Bs[2][128 * 32];
  const int tid = threadIdx.x, ln = tid & 63, wv = tid >> 6;
  const int mw = (wv >> 1) * 32, nw = (wv & 1) * 64;
  const int l15 = ln & 15, lg = ln >> 4;
  const bf16* gA = at_t + ((size_t)b * 1024 + i0) * 512;
  const bf16* gB = wp + (size_t)c0 * 512;
  f32x4 acc[2][4] = {};
  async_stage_64x32(gA, As[0], tid);
  async_stage_128x32(gB, Bs[0], tid);
  for (int it = 0; it < 16; ++it) {
    __syncthreads();
    const int cur = it & 1, nxt = cur ^ 1;
    if (it < 15) {
      async_stage_64x32(gA + (it + 1) * 32, As[nxt], tid);
      async_stage_128x32(gB + (it + 1) * 32, Bs[nxt], tid);
    }
    bf16x8 af[2], bfr[4];
#pragma unroll
    for (int mi = 0; mi < 2; ++mi)
      af[mi] = *(const bf16x8*)(&As[cur][(mw + mi * 16 + l15) * 32 + lg * 8]);
#pragma unroll
    for (int nj = 0; nj < 4; ++nj)
      bfr[nj] = *(const bf16x8*)(&Bs[cur][(nw + nj * 16 + l15) * 32 + lg * 8]);
#pragma unroll
    for (int mi = 0; mi < 2; ++mi)
#pragma unroll
      for (int nj = 0; nj < 4; ++nj)
        acc[mi][nj] = MFMA_16x16x32(af[mi], bfr[nj], acc[mi][nj]);
  }
#pragma unroll
  for (int mi = 0; mi < 2; ++mi) {
    const int i = i0 + mw + mi * 16 + lg * 4;
#pragma unroll
    for (int nj = 0; nj < 4; ++nj) {
      const int c = c0 + nw + nj * 16 + l15;
      const float bias = proj_b[c];
      const size_t off = ((size_t)b * 512 + c) * 1024 + i;
      const float4 res = *(const float4*)(x + off);
      f32x4 v = acc[mi][nj];
      float4 ov;
      ov.x = v.x + bias + res.x;
      ov.y = v.y + bias + res.y;
      ov.z = v.z + bias + res.z;
      ov.w = v.w + bias + res.w;
      *(float4*)(out + off) = ov;
    }
  }
}

// ---------------------------------------------------------------------------
extern "C" void kernel_launch(void* const* d_in, const int* in_sizes, int n_in,
                              void* d_out, int out_size, void* d_ws, size_t ws_size,
                              hipStream_t stream) {
  (void)in_sizes; (void)n_in; (void)out_size; (void)ws_size;
  const float* x      = (const float*)d_in[0];
  const float* gn_w   = (const float*)d_in[1];
  const float* gn_b   = (const float*)d_in[2];
  const float* qkv_w  = (const float*)d_in[3];
  const float* qkv_b  = (const float*)d_in[4];
  const float* proj_w = (const float*)d_in[5];
  const float* proj_b = (const float*)d_in[6];
  float* out = (float*)d_out;

  // workspace layout (~100 MB)
  char* ws = (char*)d_ws;
  bf16* wq    = (bf16*)ws;                          // [1536][512]
  bf16* wp    = wq + (size_t)1536 * 512;            // [512][512]
  bf16* xn_t  = wp + (size_t)512 * 512;             // [8][1024][512]
  bf16* qkv_t = xn_t + (size_t)8 * 1024 * 512;      // [8][1024][1536] (Q,K only)
  bf16* at_t  = qkv_t + (size_t)8 * 1024 * 1536;    // [8][1024][512]
  bf16* v_t   = at_t + (size_t)8 * 1024 * 512;      // [8][8][64][1024]

  hipLaunchKernelGGL(gn_fused_kernel, dim3(1280),     dim3(256), 0, stream,
                     x, gn_w, gn_b, qkv_w, proj_w, wq, wp, xn_t);
  hipLaunchKernelGGL(qkv_gemm_kernel, dim3(768),      dim3(256), 0, stream,
                     wq, xn_t, qkv_b, qkv_t, v_t);
  hipLaunchKernelGGL(attn_kernel,     dim3(64, 8),    dim3(512), 0, stream,
                     qkv_t, v_t, at_t);
  hipLaunchKernelGGL(proj_gemm_kernel,dim3(16, 4, 8), dim3(256), 0, stream,
                     at_t, wp, proj_b, x, out);
}

// Round 8
// 155.469 us; speedup vs baseline: 1.2071x; 1.0039x over previous
//
#include <hip/hip_runtime.h>

// ---------------------------------------------------------------------------
// AttentionBlock: GroupNorm -> QKV 1x1 conv -> MHA (8 heads, d=64, N=1024)
//               -> proj 1x1 conv -> +residual
// Shapes: B=8, C=512, H=W=32 (N=1024), groups=32, heads=8, hd=64. fp32 I/O.
// R18->R19: (1) qkv swizzle reverted (R18: +1.9us, no gain -- per-batch set
// already L2-fits). (2) attn stays R12-exact (measured best). (3) proj
// re-tiled 64x128 -> 64x64: grid 512->1024 blocks, 2->4 blocks/CU, 8->16
// waves/CU. Proj is HBM-bound (40MB traffic, floor ~6.5us) and was
// TLP-starved; wp re-reads are L2-hits (0.5MB). LDS 24->16KB.
// ---------------------------------------------------------------------------

typedef __bf16 bf16;
typedef __bf16 bf16x8 __attribute__((ext_vector_type(8)));
typedef __bf16 bf16x4 __attribute__((ext_vector_type(4)));
typedef float  f32x4  __attribute__((ext_vector_type(4)));
typedef float  f32x16 __attribute__((ext_vector_type(16)));
typedef unsigned u32x4 __attribute__((ext_vector_type(4)));

#define MFMA_16x16x32(A, B, C) __builtin_amdgcn_mfma_f32_16x16x32_bf16((A), (B), (C), 0, 0, 0)
#define MFMA_32x32x16(A, B, C) __builtin_amdgcn_mfma_f32_32x32x16_bf16((A), (B), (C), 0, 0, 0)

static __device__ __forceinline__ unsigned cvt_pk_bf16(float a, float b) {
  unsigned r;
  asm("v_cvt_pk_bf16_f32 %0, %1, %2" : "=v"(r) : "v"(a), "v"(b));
  return r;
}

// Stage a 128-row x 32-k bf16 tile (rows stride 512 in global) into LDS via
// async global_load_lds width=16.
static __device__ __forceinline__ void async_stage_128x32(
    const bf16* __restrict__ g0, bf16* lds, int tid) {
  const int wv = tid >> 6, ln = tid & 63;
#pragma unroll
  for (int cc = 0; cc < 2; ++cc) {
    const int c = wv + cc * 4;                       // wave-uniform chunk id
    const bf16* g = g0 + (size_t)(c * 16 + (ln >> 2)) * 512 + (ln & 3) * 8;
    __builtin_amdgcn_global_load_lds(
        (const __attribute__((address_space(1))) void*)g,
        (__attribute__((address_space(3))) void*)(lds + c * 512),
        16, 0, 0);
  }
}

// 64-row variant (one 16-row chunk per wave).
static __device__ __forceinline__ void async_stage_64x32(
    const bf16* __restrict__ g0, bf16* lds, int tid) {
  const int wv = tid >> 6, ln = tid & 63;
  const bf16* g = g0 + (size_t)(wv * 16 + (ln >> 2)) * 512 + (ln & 3) * 8;
  __builtin_amdgcn_global_load_lds(
      (const __attribute__((address_space(1))) void*)g,
      (__attribute__((address_space(3))) void*)(lds + wv * 512),
      16, 0, 0);
}

// ---------------------------------------------------------------------------
// Kernel 1: fused GroupNorm (stats + apply + transpose) and weight cvt.
__global__ __launch_bounds__(256) void gn_fused_kernel(
    const float* __restrict__ x,
    const float* __restrict__ gn_w, const float* __restrict__ gn_b,
    const float* __restrict__ qw, const float* __restrict__ pw,
    bf16* __restrict__ wq, bf16* __restrict__ wp, bf16* __restrict__ xn_t) {
  const int t = threadIdx.x;
  if (blockIdx.x >= 256) {
    const int idx = (blockIdx.x - 256) * 256 + t;    // float4 id
    if (idx < 196608) {                              // 1536*512/4
      float4 v = ((const float4*)qw)[idx];
      bf16x4 o = { (bf16)v.x, (bf16)v.y, (bf16)v.z, (bf16)v.w };
      *(bf16x4*)(&wq[idx * 4]) = o;
    }
    if (idx < 65536) {                               // 512*512/4
      float4 v = ((const float4*)pw)[idx];
      bf16x4 o = { (bf16)v.x, (bf16)v.y, (bf16)v.z, (bf16)v.w };
      *(bf16x4*)(&wp[idx * 4]) = o;
    }
    return;
  }
  const int bg = blockIdx.x;                        // 0..255
  const int b = bg >> 5, g = bg & 31;
  const int c0 = g * 16;
  const float4* p = (const float4*)(x + ((size_t)b * 512 + c0) * 1024);
  float4 v[16];
  float s = 0.f, s2 = 0.f;
#pragma unroll
  for (int i = 0; i < 16; ++i) {                     // c=i, n=4t..4t+3
    v[i] = p[t + 256 * i];
    s  += (v[i].x + v[i].y) + (v[i].z + v[i].w);
    s2 += (v[i].x * v[i].x + v[i].y * v[i].y) + (v[i].z * v[i].z + v[i].w * v[i].w);
  }
#pragma unroll
  for (int d = 1; d < 64; d <<= 1) {
    s  += __shfl_xor(s,  d);
    s2 += __shfl_xor(s2, d);
  }
  __shared__ float as[4], as2[4];
  __shared__ float scs[16], shs[16];
  if ((t & 63) == 0) { as[t >> 6] = s; as2[t >> 6] = s2; }
  __syncthreads();
  if (t < 16) {
    float S  = as[0] + as[1] + as[2] + as[3];
    float S2 = as2[0] + as2[1] + as2[2] + as2[3];
    float m  = S * (1.0f / 16384.0f);
    float rs = rsqrtf(S2 * (1.0f / 16384.0f) - m * m + 1e-5f);
    float sc = rs * gn_w[c0 + t];
    scs[t] = sc;
    shs[t] = gn_b[c0 + t] - m * sc;
  }
  __syncthreads();
  bf16* ob = xn_t + ((size_t)b * 1024 + 4 * t) * 512 + c0;
#pragma unroll
  for (int j = 0; j < 4; ++j) {                      // n = 4t + j
    bf16 tmp[16];
#pragma unroll
    for (int i = 0; i < 16; ++i) {
      float val = (j == 0) ? v[i].x : (j == 1) ? v[i].y : (j == 2) ? v[i].z : v[i].w;
      tmp[i] = (bf16)(val * scs[i] + shs[i]);
    }
    *(bf16x8*)(ob + (size_t)j * 512)     = *(bf16x8*)(tmp);
    *(bf16x8*)(ob + (size_t)j * 512 + 8) = *(bf16x8*)(tmp + 8);
  }
}

// ---------------------------------------------------------------------------
// Kernel 2: QKV GEMM, single-barrier dbuf K-loop (BK=32, 16 iters).
// Q rows (o<512) pre-scaled by 0.125*log2(e). Q,K -> qkv_t token-major.
// V blocks swap MFMA operands (D^T) so the v_t[b][h][d][n] store is
// vectorized bf16x4 along n.
__global__ __launch_bounds__(256) void qkv_gemm_kernel(
    const bf16* __restrict__ W, const bf16* __restrict__ xn_t,
    const float* __restrict__ qkv_b, bf16* __restrict__ qkv_t,
    bf16* __restrict__ v_t) {
  const int n0 = blockIdx.x * 128;
  const int o0 = blockIdx.y * 128;
  const int b  = blockIdx.z;
  __shared__ bf16 As[2][128 * 32];
  __shared__ bf16 Bs[2][128 * 32];
  const int tid = threadIdx.x, ln = tid & 63, wv = tid >> 6;
  const int mw = (wv >> 1) * 64, nw = (wv & 1) * 64;
  const int l15 = ln & 15, lg = ln >> 4;
  const bool isV = (o0 >= 1024);
  const bf16* gA = W + (size_t)o0 * 512;
  const bf16* gB = xn_t + ((size_t)b * 1024 + n0) * 512;
  f32x4 acc[4][4] = {};
  async_stage_128x32(gA, As[0], tid);
  async_stage_128x32(gB, Bs[0], tid);
  for (int it = 0; it < 16; ++it) {
    __syncthreads();                                 // publish buf[cur]
    const int cur = it & 1, nxt = cur ^ 1;
    if (it < 15) {                                   // prefetch overlaps compute
      async_stage_128x32(gA + (it + 1) * 32, As[nxt], tid);
      async_stage_128x32(gB + (it + 1) * 32, Bs[nxt], tid);
    }
    bf16x8 af[4], bfr[4];
#pragma unroll
    for (int mi = 0; mi < 4; ++mi)
      af[mi] = *(const bf16x8*)(&As[cur][(mw + mi * 16 + l15) * 32 + lg * 8]);
#pragma unroll
    for (int nj = 0; nj < 4; ++nj)
      bfr[nj] = *(const bf16x8*)(&Bs[cur][(nw + nj * 16 + l15) * 32 + lg * 8]);
    if (!isV) {
#pragma unroll
      for (int mi = 0; mi < 4; ++mi)
#pragma unroll
        for (int nj = 0; nj < 4; ++nj)
          acc[mi][nj] = MFMA_16x16x32(af[mi], bfr[nj], acc[mi][nj]);
    } else {                                         // swapped: acc = D^T
#pragma unroll
      for (int mi = 0; mi < 4; ++mi)
#pragma unroll
        for (int nj = 0; nj < 4; ++nj)
          acc[mi][nj] = MFMA_16x16x32(bfr[nj], af[mi], acc[mi][nj]);
    }
  }
  if (!isV) {
    const float qs = (o0 < 512) ? 0.125f * 1.44269504089f : 1.0f;
#pragma unroll
    for (int mi = 0; mi < 4; ++mi) {
      const int o = o0 + mw + mi * 16 + lg * 4;
      const float b0 = qkv_b[o], b1 = qkv_b[o + 1], b2 = qkv_b[o + 2], b3 = qkv_b[o + 3];
#pragma unroll
      for (int nj = 0; nj < 4; ++nj) {
        const int n = n0 + nw + nj * 16 + l15;
        f32x4 v = acc[mi][nj];
        bf16x4 st = { (bf16)((v.x + b0) * qs), (bf16)((v.y + b1) * qs),
                      (bf16)((v.z + b2) * qs), (bf16)((v.w + b3) * qs) };
        *(bf16x4*)(&qkv_t[((size_t)b * 1024 + n) * 1536 + o]) = st;
      }
    }
  } else {
    // swapped C-layout: lane holds D[n = nw+nj*16+lg*4+r][o = mw+mi*16+l15]
#pragma unroll
    for (int mi = 0; mi < 4; ++mi) {
      const int o  = o0 + mw + mi * 16 + l15;
      const int hd = o - 1024;                       // h*64 + d
      const float bias = qkv_b[o];
#pragma unroll
      for (int nj = 0; nj < 4; ++nj) {
        const int n = n0 + nw + nj * 16 + lg * 4;
        f32x4 v = acc[mi][nj];
        bf16x4 st = { (bf16)(v.x + bias), (bf16)(v.y + bias),
                      (bf16)(v.z + bias), (bf16)(v.w + bias) };
        *(bf16x4*)(&v_t[((size_t)b * 512 + hd) * 1024 + n]) = st;
      }
    }
  }
}

// ---------------------------------------------------------------------------
// Kernel 3: fused attention (R12-exact, measured best). 8 waves = 2
// kv-halves x 4 q-subtiles(32 q). Swapped QK^T (mfma(K,Q)) gives S^T
// (col=q=lane&31, row=kv=(r&3)+8*(r>>2)+4*(lane>>5)); exp2 in regs;
// P->B-frag via v_cvt_pk_bf16_f32 + v_permlane32_swap_b32 (no P LDS round
// trip). K/V double-buffered in LDS, ONE barrier per tile, reg-prefetch
// issued right after the barrier (T14). Halves combine O/l via f32 LDS
// exchange at the end.
__global__ __launch_bounds__(512, 4) void attn_kernel(
    const bf16* __restrict__ qkv_t, const bf16* __restrict__ v_t,
    bf16* __restrict__ at_t) {
  const int qt = blockIdx.y;                        // 0..7 (128 q each)
  const int b  = blockIdx.x >> 3;
  const int h  = blockIdx.x & 7;
  __shared__ __align__(16) char smem[73728];        // 2 bufs x 2 halves x (K+V)
  const int tid = threadIdx.x, ln = tid & 63, wv = tid >> 6;
  const int half = wv >> 2, w4 = wv & 3;
  const int l31 = ln & 31, hi = ln >> 5;
  const bf16* hq  = qkv_t + (size_t)b * 1024 * 1536 + h * 64;
  const bf16* hk  = hq + 512;
  const bf16* vtb = v_t + (size_t)(b * 8 + h) * 64 * 1024;

  const int qb = qt * 128 + w4 * 32;
  // Q B-fragments: lane holds q=l31, d = ks*16 + hi*8 + j
  bf16x8 qf[4];
#pragma unroll
  for (int ks = 0; ks < 4; ++ks)
    qf[ks] = *(const bf16x8*)(hq + (size_t)(qb + l31) * 1536 + ks * 16 + hi * 8);

  f32x16 oacc[2] = {};                              // O^T[d-tile][q]
  float lst = 0.f;

  const int t256 = tid & 255;
  const int srow = t256 >> 2, scg = (t256 & 3) * 16;
  const int kt0 = half * 8;

  // prologue: stage kv-tile kt0 into buf 0
  bf16x8 s0, s1, s2, s3;
  {
    const bf16* gk = hk  + (size_t)(kt0 * 64 + srow) * 1536 + scg;
    const bf16* gv = vtb + (size_t)srow * 1024 + kt0 * 64 + scg;
    s0 = *(const bf16x8*)(gk);
    s1 = *(const bf16x8*)(gk + 8);
    s2 = *(const bf16x8*)(gv);
    s3 = *(const bf16x8*)(gv + 8);
    bf16* Kt = (bf16*)(smem + half * 18432);
    bf16* Vt = Kt + 64 * 72;
    *(bf16x8*)(&Kt[srow * 72 + scg])     = s0;
    *(bf16x8*)(&Kt[srow * 72 + scg + 8]) = s1;
    *(bf16x8*)(&Vt[srow * 72 + scg])     = s2;
    *(bf16x8*)(&Vt[srow * 72 + scg + 8]) = s3;
  }

  for (int i = 0; i < 8; ++i) {
    __syncthreads();                                 // publish buf[i&1]
    if (i < 7) {                                     // issue prefetch NOW,
      const int kt = kt0 + i + 1;                    // consumed after compute
      const bf16* gk = hk  + (size_t)(kt * 64 + srow) * 1536 + scg;
      const bf16* gv = vtb + (size_t)srow * 1024 + kt * 64 + scg;
      s0 = *(const bf16x8*)(gk);
      s1 = *(const bf16x8*)(gk + 8);
      s2 = *(const bf16x8*)(gv);
      s3 = *(const bf16x8*)(gv + 8);
    }
    const bf16* Kt = (const bf16*)(smem + (i & 1) * 36864 + half * 18432);
    const bf16* Vt = Kt + 64 * 72;

#pragma unroll
    for (int kk = 0; kk < 2; ++kk) {
      const int kvb = kk * 32;
      f32x16 st = {};
#pragma unroll
      for (int ks = 0; ks < 4; ++ks) {
        bf16x8 kf = *(const bf16x8*)(&Kt[(kvb + l31) * 72 + ks * 16 + hi * 8]);
        st = MFMA_32x32x16(kf, qf[ks], st);
      }
#pragma unroll
      for (int r = 0; r < 16; ++r) st[r] = exp2f(st[r]);
      lst += ((st[0] + st[1]) + (st[2] + st[3])) + ((st[4] + st[5]) + (st[6] + st[7]))
           + ((st[8] + st[9]) + (st[10] + st[11])) + ((st[12] + st[13]) + (st[14] + st[15]));
#pragma unroll
      for (int t = 0; t < 2; ++t) {
        // own regs hold kv rows crow(r,hi); swap lane-halves to build B-frag
        // (lane needs kv = t*16 + hi*8 + j). After swap: {x0,x1,y0,y1} are
        // the 4 B-frag words in order.
        unsigned x0 = cvt_pk_bf16(st[t * 8 + 0], st[t * 8 + 1]);
        unsigned x1 = cvt_pk_bf16(st[t * 8 + 2], st[t * 8 + 3]);
        unsigned y0 = cvt_pk_bf16(st[t * 8 + 4], st[t * 8 + 5]);
        unsigned y1 = cvt_pk_bf16(st[t * 8 + 6], st[t * 8 + 7]);
        asm("v_permlane32_swap_b32 %0, %1" : "+v"(x0), "+v"(y0));
        asm("v_permlane32_swap_b32 %0, %1" : "+v"(x1), "+v"(y1));
        u32x4 pu = { x0, x1, y0, y1 };
        bf16x8 pb = __builtin_bit_cast(bf16x8, pu);
#pragma unroll
        for (int dt = 0; dt < 2; ++dt) {
          bf16x8 vf = *(const bf16x8*)(&Vt[(dt * 32 + l31) * 72 + kvb + t * 16 + hi * 8]);
          oacc[dt] = MFMA_32x32x16(vf, pb, oacc[dt]);
        }
      }
    }

    if (i < 7) {                                     // store prefetched tile
      bf16* Ktn = (bf16*)(smem + ((i + 1) & 1) * 36864 + half * 18432);
      bf16* Vtn = Ktn + 64 * 72;
      *(bf16x8*)(&Ktn[srow * 72 + scg])     = s0;
      *(bf16x8*)(&Ktn[srow * 72 + scg + 8]) = s1;
      *(bf16x8*)(&Vtn[srow * 72 + scg])     = s2;
      *(bf16x8*)(&Vtn[srow * 72 + scg + 8]) = s3;
    }
  }

  // lanes l / l+32 hold complementary kv rows for the same q (within half)
  const float lf = lst + __shfl_xor(lst, 32);

  // combine halves: half 1 publishes O^T + l via LDS; half 0 merges+stores.
  float* MB  = (float*)smem;                        // [w4][32 q][68 d-stride]
  float* MLb = (float*)(smem + 34816);              // [w4][32]
  __syncthreads();
  if (half == 1) {
    float* mb = MB + w4 * (32 * 68);
#pragma unroll
    for (int dt = 0; dt < 2; ++dt)
#pragma unroll
      for (int rr = 0; rr < 4; ++rr) {
        f32x4 v = { oacc[dt][rr * 4 + 0], oacc[dt][rr * 4 + 1],
                    oacc[dt][rr * 4 + 2], oacc[dt][rr * 4 + 3] };
        *(f32x4*)(mb + l31 * 68 + dt * 32 + rr * 8 + hi * 4) = v;
      }
    if (hi == 0) MLb[w4 * 32 + l31] = lf;
  }
  __syncthreads();
  if (half == 0) {
    const float* mb = MB + w4 * (32 * 68);
    const float inv = 1.0f / (lf + MLb[w4 * 32 + l31]);
    const int q = qb + l31;
    bf16* ob = at_t + ((size_t)b * 1024 + q) * 512 + h * 64;
#pragma unroll
    for (int dt = 0; dt < 2; ++dt)
#pragma unroll
      for (int rr = 0; rr < 4; ++rr) {
        f32x4 obv = *(const f32x4*)(mb + l31 * 68 + dt * 32 + rr * 8 + hi * 4);
        bf16x4 ov = { (bf16)((oacc[dt][rr * 4 + 0] + obv[0]) * inv),
                      (bf16)((oacc[dt][rr * 4 + 1] + obv[1]) * inv),
                      (bf16)((oacc[dt][rr * 4 + 2] + obv[2]) * inv),
                      (bf16)((oacc[dt][rr * 4 + 3] + obv[3]) * inv) };
        *(bf16x4*)(ob + dt * 32 + rr * 8 + hi * 4) = ov;
      }
  }
}

// ---------------------------------------------------------------------------
// Kernel 4: proj GEMM + bias + residual. BM=64, BN=64, single-barrier dbuf
// (BK=32). Grid 16x8x8 = 1024 blocks x 4 waves -> 4 blocks/CU, 16 waves/CU
// (2x R18) to hide HBM latency on this memory-bound kernel. wp re-reads
// are L2-hits (0.5 MB total).
__global__ __launch_bounds__(256) void proj_gemm_kernel(
    const bf16* __restrict__ at_t, const bf16* __restrict__ wp,
    const float* __restrict__ proj_b, const float* __restrict__ x,
    float* __restrict__ out) {
  const int i0 = blockIdx.x * 64;                   // token tile (64)
  const int c0 = blockIdx.y * 64;                   // out-channel tile (64)
  const int b  = blockIdx.z;
  __shared__ bf16 As[2][64 * 32];
  __shared__ bf16 Bs[2][64 * 32];
  const int tid = threadIdx.x, ln = tid & 63, wv = tid >> 6;
  const int mw = (wv >> 1) * 32, nw = (wv & 1) * 32;
  const int l15 = ln & 15, lg = ln >> 4;
  const bf16* gA = at_t + ((size_t)b * 1024 + i0) * 512;
  const bf16* gB = wp + (size_t)c0 * 512;
  f32x4 acc[2][2] = {};
  async_stage_64x32(gA, As[0], tid);
  async_stage_64x32(gB, Bs[0], tid);
  for (int it = 0; it < 16; ++it) {
    __syncthreads();
    const int cur = it & 1, nxt = cur ^ 1;
    if (it < 15) {
      async_stage_64x32(gA + (it + 1) * 32, As[nxt], tid);
      async_stage_64x32(gB + (it + 1) * 32, Bs[nxt], tid);
    }
    bf16x8 af[2], bfr[2];
#pragma unroll
    for (int mi = 0; mi < 2; ++mi)
      af[mi] = *(const bf16x8*)(&As[cur][(mw + mi * 16 + l15) * 32 + lg * 8]);
#pragma unroll
    for (int nj = 0; nj < 2; ++nj)
      bfr[nj] = *(const bf16x8*)(&Bs[cur][(nw + nj * 16 + l15) * 32 + lg * 8]);
#pragma unroll
    for (int mi = 0; mi < 2; ++mi)
#pragma unroll
      for (int nj = 0; nj < 2; ++nj)
        acc[mi][nj] = MFMA_16x16x32(af[mi], bfr[nj], acc[mi][nj]);
  }
#pragma unroll
  for (int mi = 0; mi < 2; ++mi) {
    const int i = i0 + mw + mi * 16 + lg * 4;
#pragma unroll
    for (int nj = 0; nj < 2; ++nj) {
      const int c = c0 + nw + nj * 16 + l15;
      const float bias = proj_b[c];
      const size_t off = ((size_t)b * 512 + c) * 1024 + i;
      const float4 res = *(const float4*)(x + off);
      f32x4 v = acc[mi][nj];
      float4 ov;
      ov.x = v.x + bias + res.x;
      ov.y = v.y + bias + res.y;
      ov.z = v.z + bias + res.z;
      ov.w = v.w + bias + res.w;
      *(float4*)(out + off) = ov;
    }
  }
}

// ---------------------------------------------------------------------------
extern "C" void kernel_launch(void* const* d_in, const int* in_sizes, int n_in,
                              void* d_out, int out_size, void* d_ws, size_t ws_size,
                              hipStream_t stream) {
  (void)in_sizes; (void)n_in; (void)out_size; (void)ws_size;
  const float* x      = (const float*)d_in[0];
  const float* gn_w   = (const float*)d_in[1];
  const float* gn_b   = (const float*)d_in[2];
  const float* qkv_w  = (const float*)d_in[3];
  const float* qkv_b  = (const float*)d_in[4];
  const float* proj_w = (const float*)d_in[5];
  const float* proj_b = (const float*)d_in[6];
  float* out = (float*)d_out;

  // workspace layout (~100 MB)
  char* ws = (char*)d_ws;
  bf16* wq    = (bf16*)ws;                          // [1536][512]
  bf16* wp    = wq + (size_t)1536 * 512;            // [512][512]
  bf16* xn_t  = wp + (size_t)512 * 512;             // [8][1024][512]
  bf16* qkv_t = xn_t + (size_t)8 * 1024 * 512;      // [8][1024][1536] (Q,K only)
  bf16* at_t  = qkv_t + (size_t)8 * 1024 * 1536;    // [8][1024][512]
  bf16* v_t   = at_t + (size_t)8 * 1024 * 512;      // [8][8][64][1024]

  hipLaunchKernelGGL(gn_fused_kernel, dim3(1280),     dim3(256), 0, stream,
                     x, gn_w, gn_b, qkv_w, proj_w, wq, wp, xn_t);
  hipLaunchKernelGGL(qkv_gemm_kernel, dim3(8, 12, 8), dim3(256), 0, stream,
                     wq, xn_t, qkv_b, qkv_t, v_t);
  hipLaunchKernelGGL(attn_kernel,     dim3(64, 8),    dim3(512), 0, stream,
                     qkv_t, v_t, at_t);
  hipLaunchKernelGGL(proj_gemm_kernel,dim3(16, 8, 8), dim3(256), 0, stream,
                     at_t, wp, proj_b, x, out);
}

// Round 9
// 153.503 us; speedup vs baseline: 1.2226x; 1.0128x over previous
//
#include <hip/hip_runtime.h>

// ---------------------------------------------------------------------------
// AttentionBlock: GroupNorm -> QKV 1x1 conv -> MHA (8 heads, d=64, N=1024)
//               -> proj 1x1 conv -> +residual
// Shapes: B=8, C=512, H=W=32 (N=1024), groups=32, heads=8, hd=64. fp32 I/O.
// R19->R20: FINAL — revert to the measured-best R12 configuration in all
// four kernels (proj back to 64x128 tile, grid (16,4,8)). Session ledger:
// R12=154.2 best; tested-and-rejected: attn setprio (+2.5), attn 4-wave
// full-sweep (+3), attn bank-swizzle+gload_lds (±0), attn unstaged (+33),
// qkv XCD swizzle (+1.9), proj 64x64 retile (+1.3). Pipeline model:
// fills 86us (HBM-roofline, harness-fixed) + gn 6 + qkv 14 (m97 ceiling)
// + attn 36 + proj 11 = 153 ~= measurement.
// ---------------------------------------------------------------------------

typedef __bf16 bf16;
typedef __bf16 bf16x8 __attribute__((ext_vector_type(8)));
typedef __bf16 bf16x4 __attribute__((ext_vector_type(4)));
typedef float  f32x4  __attribute__((ext_vector_type(4)));
typedef float  f32x16 __attribute__((ext_vector_type(16)));
typedef unsigned u32x4 __attribute__((ext_vector_type(4)));

#define MFMA_16x16x32(A, B, C) __builtin_amdgcn_mfma_f32_16x16x32_bf16((A), (B), (C), 0, 0, 0)
#define MFMA_32x32x16(A, B, C) __builtin_amdgcn_mfma_f32_32x32x16_bf16((A), (B), (C), 0, 0, 0)

static __device__ __forceinline__ unsigned cvt_pk_bf16(float a, float b) {
  unsigned r;
  asm("v_cvt_pk_bf16_f32 %0, %1, %2" : "=v"(r) : "v"(a), "v"(b));
  return r;
}

// Stage a 128-row x 32-k bf16 tile (rows stride 512 in global) into LDS via
// async global_load_lds width=16.
static __device__ __forceinline__ void async_stage_128x32(
    const bf16* __restrict__ g0, bf16* lds, int tid) {
  const int wv = tid >> 6, ln = tid & 63;
#pragma unroll
  for (int cc = 0; cc < 2; ++cc) {
    const int c = wv + cc * 4;                       // wave-uniform chunk id
    const bf16* g = g0 + (size_t)(c * 16 + (ln >> 2)) * 512 + (ln & 3) * 8;
    __builtin_amdgcn_global_load_lds(
        (const __attribute__((address_space(1))) void*)g,
        (__attribute__((address_space(3))) void*)(lds + c * 512),
        16, 0, 0);
  }
}

// 64-row variant (one 16-row chunk per wave).
static __device__ __forceinline__ void async_stage_64x32(
    const bf16* __restrict__ g0, bf16* lds, int tid) {
  const int wv = tid >> 6, ln = tid & 63;
  const bf16* g = g0 + (size_t)(wv * 16 + (ln >> 2)) * 512 + (ln & 3) * 8;
  __builtin_amdgcn_global_load_lds(
      (const __attribute__((address_space(1))) void*)g,
      (__attribute__((address_space(3))) void*)(lds + wv * 512),
      16, 0, 0);
}

// ---------------------------------------------------------------------------
// Kernel 1: fused GroupNorm (stats + apply + transpose) and weight cvt.
__global__ __launch_bounds__(256) void gn_fused_kernel(
    const float* __restrict__ x,
    const float* __restrict__ gn_w, const float* __restrict__ gn_b,
    const float* __restrict__ qw, const float* __restrict__ pw,
    bf16* __restrict__ wq, bf16* __restrict__ wp, bf16* __restrict__ xn_t) {
  const int t = threadIdx.x;
  if (blockIdx.x >= 256) {
    const int idx = (blockIdx.x - 256) * 256 + t;    // float4 id
    if (idx < 196608) {                              // 1536*512/4
      float4 v = ((const float4*)qw)[idx];
      bf16x4 o = { (bf16)v.x, (bf16)v.y, (bf16)v.z, (bf16)v.w };
      *(bf16x4*)(&wq[idx * 4]) = o;
    }
    if (idx < 65536) {                               // 512*512/4
      float4 v = ((const float4*)pw)[idx];
      bf16x4 o = { (bf16)v.x, (bf16)v.y, (bf16)v.z, (bf16)v.w };
      *(bf16x4*)(&wp[idx * 4]) = o;
    }
    return;
  }
  const int bg = blockIdx.x;                        // 0..255
  const int b = bg >> 5, g = bg & 31;
  const int c0 = g * 16;
  const float4* p = (const float4*)(x + ((size_t)b * 512 + c0) * 1024);
  float4 v[16];
  float s = 0.f, s2 = 0.f;
#pragma unroll
  for (int i = 0; i < 16; ++i) {                     // c=i, n=4t..4t+3
    v[i] = p[t + 256 * i];
    s  += (v[i].x + v[i].y) + (v[i].z + v[i].w);
    s2 += (v[i].x * v[i].x + v[i].y * v[i].y) + (v[i].z * v[i].z + v[i].w * v[i].w);
  }
#pragma unroll
  for (int d = 1; d < 64; d <<= 1) {
    s  += __shfl_xor(s,  d);
    s2 += __shfl_xor(s2, d);
  }
  __shared__ float as[4], as2[4];
  __shared__ float scs[16], shs[16];
  if ((t & 63) == 0) { as[t >> 6] = s; as2[t >> 6] = s2; }
  __syncthreads();
  if (t < 16) {
    float S  = as[0] + as[1] + as[2] + as[3];
    float S2 = as2[0] + as2[1] + as2[2] + as2[3];
    float m  = S * (1.0f / 16384.0f);
    float rs = rsqrtf(S2 * (1.0f / 16384.0f) - m * m + 1e-5f);
    float sc = rs * gn_w[c0 + t];
    scs[t] = sc;
    shs[t] = gn_b[c0 + t] - m * sc;
  }
  __syncthreads();
  bf16* ob = xn_t + ((size_t)b * 1024 + 4 * t) * 512 + c0;
#pragma unroll
  for (int j = 0; j < 4; ++j) {                      // n = 4t + j
    bf16 tmp[16];
#pragma unroll
    for (int i = 0; i < 16; ++i) {
      float val = (j == 0) ? v[i].x : (j == 1) ? v[i].y : (j == 2) ? v[i].z : v[i].w;
      tmp[i] = (bf16)(val * scs[i] + shs[i]);
    }
    *(bf16x8*)(ob + (size_t)j * 512)     = *(bf16x8*)(tmp);
    *(bf16x8*)(ob + (size_t)j * 512 + 8) = *(bf16x8*)(tmp + 8);
  }
}

// ---------------------------------------------------------------------------
// Kernel 2: QKV GEMM, single-barrier dbuf K-loop (BK=32, 16 iters).
// Q rows (o<512) pre-scaled by 0.125*log2(e). Q,K -> qkv_t token-major.
// V blocks swap MFMA operands (D^T) so the v_t[b][h][d][n] store is
// vectorized bf16x4 along n.
__global__ __launch_bounds__(256) void qkv_gemm_kernel(
    const bf16* __restrict__ W, const bf16* __restrict__ xn_t,
    const float* __restrict__ qkv_b, bf16* __restrict__ qkv_t,
    bf16* __restrict__ v_t) {
  const int n0 = blockIdx.x * 128;
  const int o0 = blockIdx.y * 128;
  const int b  = blockIdx.z;
  __shared__ bf16 As[2][128 * 32];
  __shared__ bf16 Bs[2][128 * 32];
  const int tid = threadIdx.x, ln = tid & 63, wv = tid >> 6;
  const int mw = (wv >> 1) * 64, nw = (wv & 1) * 64;
  const int l15 = ln & 15, lg = ln >> 4;
  const bool isV = (o0 >= 1024);
  const bf16* gA = W + (size_t)o0 * 512;
  const bf16* gB = xn_t + ((size_t)b * 1024 + n0) * 512;
  f32x4 acc[4][4] = {};
  async_stage_128x32(gA, As[0], tid);
  async_stage_128x32(gB, Bs[0], tid);
  for (int it = 0; it < 16; ++it) {
    __syncthreads();                                 // publish buf[cur]
    const int cur = it & 1, nxt = cur ^ 1;
    if (it < 15) {                                   // prefetch overlaps compute
      async_stage_128x32(gA + (it + 1) * 32, As[nxt], tid);
      async_stage_128x32(gB + (it + 1) * 32, Bs[nxt], tid);
    }
    bf16x8 af[4], bfr[4];
#pragma unroll
    for (int mi = 0; mi < 4; ++mi)
      af[mi] = *(const bf16x8*)(&As[cur][(mw + mi * 16 + l15) * 32 + lg * 8]);
#pragma unroll
    for (int nj = 0; nj < 4; ++nj)
      bfr[nj] = *(const bf16x8*)(&Bs[cur][(nw + nj * 16 + l15) * 32 + lg * 8]);
    if (!isV) {
#pragma unroll
      for (int mi = 0; mi < 4; ++mi)
#pragma unroll
        for (int nj = 0; nj < 4; ++nj)
          acc[mi][nj] = MFMA_16x16x32(af[mi], bfr[nj], acc[mi][nj]);
    } else {                                         // swapped: acc = D^T
#pragma unroll
      for (int mi = 0; mi < 4; ++mi)
#pragma unroll
        for (int nj = 0; nj < 4; ++nj)
          acc[mi][nj] = MFMA_16x16x32(bfr[nj], af[mi], acc[mi][nj]);
    }
  }
  if (!isV) {
    const float qs = (o0 < 512) ? 0.125f * 1.44269504089f : 1.0f;
#pragma unroll
    for (int mi = 0; mi < 4; ++mi) {
      const int o = o0 + mw + mi * 16 + lg * 4;
      const float b0 = qkv_b[o], b1 = qkv_b[o + 1], b2 = qkv_b[o + 2], b3 = qkv_b[o + 3];
#pragma unroll
      for (int nj = 0; nj < 4; ++nj) {
        const int n = n0 + nw + nj * 16 + l15;
        f32x4 v = acc[mi][nj];
        bf16x4 st = { (bf16)((v.x + b0) * qs), (bf16)((v.y + b1) * qs),
                      (bf16)((v.z + b2) * qs), (bf16)((v.w + b3) * qs) };
        *(bf16x4*)(&qkv_t[((size_t)b * 1024 + n) * 1536 + o]) = st;
      }
    }
  } else {
    // swapped C-layout: lane holds D[n = nw+nj*16+lg*4+r][o = mw+mi*16+l15]
#pragma unroll
    for (int mi = 0; mi < 4; ++mi) {
      const int o  = o0 + mw + mi * 16 + l15;
      const int hd = o - 1024;                       // h*64 + d
      const float bias = qkv_b[o];
#pragma unroll
      for (int nj = 0; nj < 4; ++nj) {
        const int n = n0 + nw + nj * 16 + lg * 4;
        f32x4 v = acc[mi][nj];
        bf16x4 st = { (bf16)(v.x + bias), (bf16)(v.y + bias),
                      (bf16)(v.z + bias), (bf16)(v.w + bias) };
        *(bf16x4*)(&v_t[((size_t)b * 512 + hd) * 1024 + n]) = st;
      }
    }
  }
}

// ---------------------------------------------------------------------------
// Kernel 3: fused attention (R12-exact, measured best). 8 waves = 2
// kv-halves x 4 q-subtiles(32 q). Swapped QK^T (mfma(K,Q)) gives S^T
// (col=q=lane&31, row=kv=(r&3)+8*(r>>2)+4*(lane>>5)); exp2 in regs;
// P->B-frag via v_cvt_pk_bf16_f32 + v_permlane32_swap_b32 (no P LDS round
// trip). K/V double-buffered in LDS, ONE barrier per tile, reg-prefetch
// issued right after the barrier (T14). Halves combine O/l via f32 LDS
// exchange at the end.
__global__ __launch_bounds__(512, 4) void attn_kernel(
    const bf16* __restrict__ qkv_t, const bf16* __restrict__ v_t,
    bf16* __restrict__ at_t) {
  const int qt = blockIdx.y;                        // 0..7 (128 q each)
  const int b  = blockIdx.x >> 3;
  const int h  = blockIdx.x & 7;
  __shared__ __align__(16) char smem[73728];        // 2 bufs x 2 halves x (K+V)
  const int tid = threadIdx.x, ln = tid & 63, wv = tid >> 6;
  const int half = wv >> 2, w4 = wv & 3;
  const int l31 = ln & 31, hi = ln >> 5;
  const bf16* hq  = qkv_t + (size_t)b * 1024 * 1536 + h * 64;
  const bf16* hk  = hq + 512;
  const bf16* vtb = v_t + (size_t)(b * 8 + h) * 64 * 1024;

  const int qb = qt * 128 + w4 * 32;
  // Q B-fragments: lane holds q=l31, d = ks*16 + hi*8 + j
  bf16x8 qf[4];
#pragma unroll
  for (int ks = 0; ks < 4; ++ks)
    qf[ks] = *(const bf16x8*)(hq + (size_t)(qb + l31) * 1536 + ks * 16 + hi * 8);

  f32x16 oacc[2] = {};                              // O^T[d-tile][q]
  float lst = 0.f;

  const int t256 = tid & 255;
  const int srow = t256 >> 2, scg = (t256 & 3) * 16;
  const int kt0 = half * 8;

  // prologue: stage kv-tile kt0 into buf 0
  bf16x8 s0, s1, s2, s3;
  {
    const bf16* gk = hk  + (size_t)(kt0 * 64 + srow) * 1536 + scg;
    const bf16* gv = vtb + (size_t)srow * 1024 + kt0 * 64 + scg;
    s0 = *(const bf16x8*)(gk);
    s1 = *(const bf16x8*)(gk + 8);
    s2 = *(const bf16x8*)(gv);
    s3 = *(const bf16x8*)(gv + 8);
    bf16* Kt = (bf16*)(smem + half * 18432);
    bf16* Vt = Kt + 64 * 72;
    *(bf16x8*)(&Kt[srow * 72 + scg])     = s0;
    *(bf16x8*)(&Kt[srow * 72 + scg + 8]) = s1;
    *(bf16x8*)(&Vt[srow * 72 + scg])     = s2;
    *(bf16x8*)(&Vt[srow * 72 + scg + 8]) = s3;
  }

  for (int i = 0; i < 8; ++i) {
    __syncthreads();                                 // publish buf[i&1]
    if (i < 7) {                                     // issue prefetch NOW,
      const int kt = kt0 + i + 1;                    // consumed after compute
      const bf16* gk = hk  + (size_t)(kt * 64 + srow) * 1536 + scg;
      const bf16* gv = vtb + (size_t)srow * 1024 + kt * 64 + scg;
      s0 = *(const bf16x8*)(gk);
      s1 = *(const bf16x8*)(gk + 8);
      s2 = *(const bf16x8*)(gv);
      s3 = *(const bf16x8*)(gv + 8);
    }
    const bf16* Kt = (const bf16*)(smem + (i & 1) * 36864 + half * 18432);
    const bf16* Vt = Kt + 64 * 72;

#pragma unroll
    for (int kk = 0; kk < 2; ++kk) {
      const int kvb = kk * 32;
      f32x16 st = {};
#pragma unroll
      for (int ks = 0; ks < 4; ++ks) {
        bf16x8 kf = *(const bf16x8*)(&Kt[(kvb + l31) * 72 + ks * 16 + hi * 8]);
        st = MFMA_32x32x16(kf, qf[ks], st);
      }
#pragma unroll
      for (int r = 0; r < 16; ++r) st[r] = exp2f(st[r]);
      lst += ((st[0] + st[1]) + (st[2] + st[3])) + ((st[4] + st[5]) + (st[6] + st[7]))
           + ((st[8] + st[9]) + (st[10] + st[11])) + ((st[12] + st[13]) + (st[14] + st[15]));
#pragma unroll
      for (int t = 0; t < 2; ++t) {
        // own regs hold kv rows crow(r,hi); swap lane-halves to build B-frag
        // (lane needs kv = t*16 + hi*8 + j). After swap: {x0,x1,y0,y1} are
        // the 4 B-frag words in order.
        unsigned x0 = cvt_pk_bf16(st[t * 8 + 0], st[t * 8 + 1]);
        unsigned x1 = cvt_pk_bf16(st[t * 8 + 2], st[t * 8 + 3]);
        unsigned y0 = cvt_pk_bf16(st[t * 8 + 4], st[t * 8 + 5]);
        unsigned y1 = cvt_pk_bf16(st[t * 8 + 6], st[t * 8 + 7]);
        asm("v_permlane32_swap_b32 %0, %1" : "+v"(x0), "+v"(y0));
        asm("v_permlane32_swap_b32 %0, %1" : "+v"(x1), "+v"(y1));
        u32x4 pu = { x0, x1, y0, y1 };
        bf16x8 pb = __builtin_bit_cast(bf16x8, pu);
#pragma unroll
        for (int dt = 0; dt < 2; ++dt) {
          bf16x8 vf = *(const bf16x8*)(&Vt[(dt * 32 + l31) * 72 + kvb + t * 16 + hi * 8]);
          oacc[dt] = MFMA_32x32x16(vf, pb, oacc[dt]);
        }
      }
    }

    if (i < 7) {                                     // store prefetched tile
      bf16* Ktn = (bf16*)(smem + ((i + 1) & 1) * 36864 + half * 18432);
      bf16* Vtn = Ktn + 64 * 72;
      *(bf16x8*)(&Ktn[srow * 72 + scg])     = s0;
      *(bf16x8*)(&Ktn[srow * 72 + scg + 8]) = s1;
      *(bf16x8*)(&Vtn[srow * 72 + scg])     = s2;
      *(bf16x8*)(&Vtn[srow * 72 + scg + 8]) = s3;
    }
  }

  // lanes l / l+32 hold complementary kv rows for the same q (within half)
  const float lf = lst + __shfl_xor(lst, 32);

  // combine halves: half 1 publishes O^T + l via LDS; half 0 merges+stores.
  float* MB  = (float*)smem;                        // [w4][32 q][68 d-stride]
  float* MLb = (float*)(smem + 34816);              // [w4][32]
  __syncthreads();
  if (half == 1) {
    float* mb = MB + w4 * (32 * 68);
#pragma unroll
    for (int dt = 0; dt < 2; ++dt)
#pragma unroll
      for (int rr = 0; rr < 4; ++rr) {
        f32x4 v = { oacc[dt][rr * 4 + 0], oacc[dt][rr * 4 + 1],
                    oacc[dt][rr * 4 + 2], oacc[dt][rr * 4 + 3] };
        *(f32x4*)(mb + l31 * 68 + dt * 32 + rr * 8 + hi * 4) = v;
      }
    if (hi == 0) MLb[w4 * 32 + l31] = lf;
  }
  __syncthreads();
  if (half == 0) {
    const float* mb = MB + w4 * (32 * 68);
    const float inv = 1.0f / (lf + MLb[w4 * 32 + l31]);
    const int q = qb + l31;
    bf16* ob = at_t + ((size_t)b * 1024 + q) * 512 + h * 64;
#pragma unroll
    for (int dt = 0; dt < 2; ++dt)
#pragma unroll
      for (int rr = 0; rr < 4; ++rr) {
        f32x4 obv = *(const f32x4*)(mb + l31 * 68 + dt * 32 + rr * 8 + hi * 4);
        bf16x4 ov = { (bf16)((oacc[dt][rr * 4 + 0] + obv[0]) * inv),
                      (bf16)((oacc[dt][rr * 4 + 1] + obv[1]) * inv),
                      (bf16)((oacc[dt][rr * 4 + 2] + obv[2]) * inv),
                      (bf16)((oacc[dt][rr * 4 + 3] + obv[3]) * inv) };
        *(bf16x4*)(ob + dt * 32 + rr * 8 + hi * 4) = ov;
      }
  }
}

// ---------------------------------------------------------------------------
// Kernel 4: proj GEMM + bias + residual. BM=64, single-barrier dbuf (BK=32).
// R12-exact: 64x128 tile, grid (16,4,8).
__global__ __launch_bounds__(256) void proj_gemm_kernel(
    const bf16* __restrict__ at_t, const bf16* __restrict__ wp,
    const float* __restrict__ proj_b, const float* __restrict__ x,
    float* __restrict__ out) {
  const int i0 = blockIdx.x * 64;                   // token tile (64)
  const int c0 = blockIdx.y * 128;                  // out-channel tile (128)
  const int b  = blockIdx.z;
  __shared__ bf16 As[2][64 * 32];
  __shared__ bf16 Bs[2][128 * 32];
  const int tid = threadIdx.x, ln = tid & 63, wv = tid >> 6;
  const int mw = (wv >> 1) * 32, nw = (wv & 1) * 64;
  const int l15 = ln & 15, lg = ln >> 4;
  const bf16* gA = at_t + ((size_t)b * 1024 + i0) * 512;
  const bf16* gB = wp + (size_t)c0 * 512;
  f32x4 acc[2][4] = {};
  async_stage_64x32(gA, As[0], tid);
  async_stage_128x32(gB, Bs[0], tid);
  for (int it = 0; it < 16; ++it) {
    __syncthreads();
    const int cur = it & 1, nxt = cur ^ 1;
    if (it < 15) {
      async_stage_64x32(gA + (it + 1) * 32, As[nxt], tid);
      async_stage_128x32(gB + (it + 1) * 32, Bs[nxt], tid);
    }
    bf16x8 af[2], bfr[4];
#pragma unroll
    for (int mi = 0; mi < 2; ++mi)
      af[mi] = *(const bf16x8*)(&As[cur][(mw + mi * 16 + l15) * 32 + lg * 8]);
#pragma unroll
    for (int nj = 0; nj < 4; ++nj)
      bfr[nj] = *(const bf16x8*)(&Bs[cur][(nw + nj * 16 + l15) * 32 + lg * 8]);
#pragma unroll
    for (int mi = 0; mi < 2; ++mi)
#pragma unroll
      for (int nj = 0; nj < 4; ++nj)
        acc[mi][nj] = MFMA_16x16x32(af[mi], bfr[nj], acc[mi][nj]);
  }
#pragma unroll
  for (int mi = 0; mi < 2; ++mi) {
    const int i = i0 + mw + mi * 16 + lg * 4;
#pragma unroll
    for (int nj = 0; nj < 4; ++nj) {
      const int c = c0 + nw + nj * 16 + l15;
      const float bias = proj_b[c];
      const size_t off = ((size_t)b * 512 + c) * 1024 + i;
      const float4 res = *(const float4*)(x + off);
      f32x4 v = acc[mi][nj];
      float4 ov;
      ov.x = v.x + bias + res.x;
      ov.y = v.y + bias + res.y;
      ov.z = v.z + bias + res.z;
      ov.w = v.w + bias + res.w;
      *(float4*)(out + off) = ov;
    }
  }
}

// ---------------------------------------------------------------------------
extern "C" void kernel_launch(void* const* d_in, const int* in_sizes, int n_in,
                              void* d_out, int out_size, void* d_ws, size_t ws_size,
                              hipStream_t stream) {
  (void)in_sizes; (void)n_in; (void)out_size; (void)ws_size;
  const float* x      = (const float*)d_in[0];
  const float* gn_w   = (const float*)d_in[1];
  const float* gn_b   = (const float*)d_in[2];
  const float* qkv_w  = (const float*)d_in[3];
  const float* qkv_b  = (const float*)d_in[4];
  const float* proj_w = (const float*)d_in[5];
  const float* proj_b = (const float*)d_in[6];
  float* out = (float*)d_out;

  // workspace layout (~100 MB)
  char* ws = (char*)d_ws;
  bf16* wq    = (bf16*)ws;                          // [1536][512]
  bf16* wp    = wq + (size_t)1536 * 512;            // [512][512]
  bf16* xn_t  = wp + (size_t)512 * 512;             // [8][1024][512]
  bf16* qkv_t = xn_t + (size_t)8 * 1024 * 512;      // [8][1024][1536] (Q,K only)
  bf16* at_t  = qkv_t + (size_t)8 * 1024 * 1536;    // [8][1024][512]
  bf16* v_t   = at_t + (size_t)8 * 1024 * 512;      // [8][8][64][1024]

  hipLaunchKernelGGL(gn_fused_kernel, dim3(1280),     dim3(256), 0, stream,
                     x, gn_w, gn_b, qkv_w, proj_w, wq, wp, xn_t);
  hipLaunchKernelGGL(qkv_gemm_kernel, dim3(8, 12, 8), dim3(256), 0, stream,
                     wq, xn_t, qkv_b, qkv_t, v_t);
  hipLaunchKernelGGL(attn_kernel,     dim3(64, 8),    dim3(512), 0, stream,
                     qkv_t, v_t, at_t);
  hipLaunchKernelGGL(proj_gemm_kernel,dim3(16, 4, 8), dim3(256), 0, stream,
                     at_t, wp, proj_b, x, out);
}